// Round 1
// baseline (3782.140 us; speedup 1.0000x reference)
//
#include <hip/hip_runtime.h>

#define N 1024
#define NE 32768
#define S 4
#define STEPS 31
#define FEAT (S * STEPS)  // 124

// ---------------------------------------------------------------------------
// Kernel 1: build the S normalized transition matrices P[s] from coords.
// One block per row i; 256 threads; each thread owns 4 columns (j = tid+256c).
// Keeps the 16 w-values (4 cols x 4 sigmas) in registers, block-reduces the
// 4 row sums in LDS, then writes normalized P. Matches reference exactly:
// w = exp(-d2/(2*sigma^2)), diag zeroed, P = w / max(rowsum, 1e-12).
// ---------------------------------------------------------------------------
__global__ __launch_bounds__(256) void build_P(const float* __restrict__ coords,
                                               const float* __restrict__ log_sigmas,
                                               float* __restrict__ P)
{
    const int i   = blockIdx.x;
    const int tid = threadIdx.x;

    // sigmas = sort(exp(log_sigmas)) ; 4-element sort network
    float sg[S];
#pragma unroll
    for (int s = 0; s < S; ++s) sg[s] = expf(log_sigmas[s]);
#define CSWP(a, b) { float lo = fminf(sg[a], sg[b]); float hi = fmaxf(sg[a], sg[b]); sg[a] = lo; sg[b] = hi; }
    CSWP(0, 1) CSWP(2, 3) CSWP(0, 2) CSWP(1, 3) CSWP(1, 2)
#undef CSWP
    float inv2s2[S];
#pragma unroll
    for (int s = 0; s < S; ++s) inv2s2[s] = 1.0f / (2.0f * sg[s] * sg[s]);

    const float cx = coords[3 * i + 0];
    const float cy = coords[3 * i + 1];
    const float cz = coords[3 * i + 2];

    float w[4][S];
    float part[S] = {0.f, 0.f, 0.f, 0.f};
#pragma unroll
    for (int c = 0; c < 4; ++c) {
        const int j = tid + c * 256;
        const float dx = cx - coords[3 * j + 0];
        const float dy = cy - coords[3 * j + 1];
        const float dz = cz - coords[3 * j + 2];
        const float d2 = dx * dx + dy * dy + dz * dz;
#pragma unroll
        for (int s = 0; s < S; ++s) {
            const float v = (j == i) ? 0.0f : expf(-d2 * inv2s2[s]);
            w[c][s] = v;
            part[s] += v;
        }
    }

    __shared__ float red[S][256];
#pragma unroll
    for (int s = 0; s < S; ++s) red[s][tid] = part[s];
    __syncthreads();
    for (int st = 128; st > 0; st >>= 1) {
        if (tid < st) {
#pragma unroll
            for (int s = 0; s < S; ++s) red[s][tid] += red[s][tid + st];
        }
        __syncthreads();
    }

    float invden[S];
#pragma unroll
    for (int s = 0; s < S; ++s) invden[s] = 1.0f / fmaxf(red[s][0], 1e-12f);

#pragma unroll
    for (int c = 0; c < 4; ++c) {
        const int j = tid + c * 256;
#pragma unroll
        for (int s = 0; s < S; ++s) {
            P[((long)s * N + i) * N + j] = w[c][s] * invden[s];
        }
    }
}

// ---------------------------------------------------------------------------
// Kernel 2: batched fp32 GEMM  C[s] = A[s] @ B[s], all 1024x1024 row-major.
// 64x64 tile, BK=16, 256 threads, 4x4 micro-tile per thread.
// ---------------------------------------------------------------------------
__global__ __launch_bounds__(256) void gemm_f32(const float* __restrict__ Ag,
                                                const float* __restrict__ Bg,
                                                float* __restrict__ Cg)
{
    const long base = (long)blockIdx.z * N * N;
    const float* A = Ag + base;
    const float* B = Bg + base;
    float*       C = Cg + base;

    const int tr  = blockIdx.y * 64;
    const int tc  = blockIdx.x * 64;
    const int tid = threadIdx.x;
    const int tx  = tid & 15;   // 0..15 -> 4 output cols each
    const int ty  = tid >> 4;   // 0..15 -> 4 output rows each

    __shared__ float As[64][17];   // [row][k], +1 pad
    __shared__ float Bs[16][64];   // [k][col]

    // staging indices: 1024 floats per tile per buffer, 1 float4 per thread
    const int arow = tid >> 2;         // 0..63
    const int akv  = (tid & 3) * 4;    // 0,4,8,12
    const int brow = tid >> 4;         // 0..15
    const int bcol = (tid & 15) * 4;   // 0..60

    float acc[4][4] = {};

    for (int k0 = 0; k0 < N; k0 += 16) {
        const float4 av = *(const float4*)&A[(long)(tr + arow) * N + k0 + akv];
        const float4 bv = *(const float4*)&B[(long)(k0 + brow) * N + tc + bcol];
        As[arow][akv + 0] = av.x;
        As[arow][akv + 1] = av.y;
        As[arow][akv + 2] = av.z;
        As[arow][akv + 3] = av.w;
        *(float4*)&Bs[brow][bcol] = bv;
        __syncthreads();

#pragma unroll
        for (int kk = 0; kk < 16; ++kk) {
            float a[4], b[4];
#pragma unroll
            for (int m = 0; m < 4; ++m) a[m] = As[ty * 4 + m][kk];
#pragma unroll
            for (int n = 0; n < 4; ++n) b[n] = Bs[kk][tx * 4 + n];
#pragma unroll
            for (int m = 0; m < 4; ++m)
#pragma unroll
                for (int n = 0; n < 4; ++n)
                    acc[m][n] = fmaf(a[m], b[n], acc[m][n]);
        }
        __syncthreads();
    }

#pragma unroll
    for (int m = 0; m < 4; ++m) {
        float4 v = make_float4(acc[m][0], acc[m][1], acc[m][2], acc[m][3]);
        *(float4*)&C[(long)(tr + ty * 4 + m) * N + tc + tx * 4] = v;
    }
}

// ---------------------------------------------------------------------------
// Kernel 3: gather diag + edge entries of P_k into output feature slot t.
// node_features[n, s*31+t] = Pk[s][n][n]
// edge_features[e, s*31+t] = Pk[s][ei[e]][ej[e]]
// ---------------------------------------------------------------------------
__global__ __launch_bounds__(256) void gather_feats(const float* __restrict__ Pk,
                                                    const int* __restrict__ eidx,
                                                    float* __restrict__ out,
                                                    int t)
{
    const int tid = blockIdx.x * blockDim.x + threadIdx.x;
    const int ND = S * N;
    if (tid < ND) {
        const int s = tid / N;
        const int n = tid % N;
        out[(long)n * FEAT + s * STEPS + t] = Pk[((long)s * N + n) * N + n];
    } else {
        const int idx = tid - ND;
        if (idx >= S * NE) return;
        const int s = idx / NE;
        const int e = idx % NE;
        const int i = eidx[e];
        const int j = eidx[NE + e];
        out[(long)N * FEAT + (long)e * FEAT + s * STEPS + t] =
            Pk[((long)s * N + i) * N + j];
    }
}

// ---------------------------------------------------------------------------
extern "C" void kernel_launch(void* const* d_in, const int* in_sizes, int n_in,
                              void* d_out, int out_size, void* d_ws, size_t ws_size,
                              hipStream_t stream)
{
    const float* coords     = (const float*)d_in[0];
    const float* log_sigmas = (const float*)d_in[1];
    const int*   eidx       = (const int*)d_in[2];
    float*       out        = (float*)d_out;

    float* P  = (float*)d_ws;                 // S*N*N fp32 = 16 MB
    float* C1 = P  + (size_t)S * N * N;       // +16 MB
    float* C2 = C1 + (size_t)S * N * N;       // +16 MB

    build_P<<<N, 256, 0, stream>>>(coords, log_sigmas, P);

    const int gather_blocks = (S * N + S * NE + 255) / 256;   // 528
    // k = 1: P^1 = P itself
    gather_feats<<<gather_blocks, 256, 0, stream>>>(P, eidx, out, 0);

    const float* cur = P;
    float* bufs[2] = {C1, C2};
    for (int k = 2; k <= STEPS; ++k) {
        float* nxt = bufs[k & 1];
        dim3 grid(N / 64, N / 64, S);
        gemm_f32<<<grid, 256, 0, stream>>>(cur, P, nxt);
        gather_feats<<<gather_blocks, 256, 0, stream>>>(nxt, eidx, out, k - 1);
        cur = nxt;
    }
}

// Round 2
// 1487.149 us; speedup vs baseline: 2.5432x; 2.5432x over previous
//
#include <hip/hip_runtime.h>

#define N 1024
#define NE 32768
#define S 4
#define STEPS 31
#define FEAT (S * STEPS)  // 124
#define SZ ((size_t)S * N * N)

typedef short short8 __attribute__((ext_vector_type(8)));
typedef float f32x4 __attribute__((ext_vector_type(4)));

// ---- bf16 helpers (RNE for finite values) --------------------------------
__device__ __forceinline__ ushort f2bf(float x) {
    union { float f; unsigned u; } v; v.f = x;
    unsigned r = v.u + 0x7fffu + ((v.u >> 16) & 1u);
    return (ushort)(r >> 16);
}
__device__ __forceinline__ float bf2f(ushort h) {
    union { unsigned u; float f; } v; v.u = ((unsigned)h) << 16;
    return v.f;
}

__device__ __forceinline__ void gload16(const ushort* g, ushort* l) {
    __builtin_amdgcn_global_load_lds(
        (const __attribute__((address_space(1))) unsigned int*)g,
        (__attribute__((address_space(3))) unsigned int*)l, 16, 0, 0);
}

// ---------------------------------------------------------------------------
// Kernel 1: build P (split bf16 hi/lo), row-major [s][i][j].
// ---------------------------------------------------------------------------
__global__ __launch_bounds__(256) void build_P(const float* __restrict__ coords,
                                               const float* __restrict__ log_sigmas,
                                               ushort* __restrict__ Oh,
                                               ushort* __restrict__ Ol)
{
    const int i   = blockIdx.x;
    const int tid = threadIdx.x;

    float sg[S];
#pragma unroll
    for (int s = 0; s < S; ++s) sg[s] = expf(log_sigmas[s]);
#define CSWP(a, b) { float lo = fminf(sg[a], sg[b]); float hi = fmaxf(sg[a], sg[b]); sg[a] = lo; sg[b] = hi; }
    CSWP(0, 1) CSWP(2, 3) CSWP(0, 2) CSWP(1, 3) CSWP(1, 2)
#undef CSWP
    float inv2s2[S];
#pragma unroll
    for (int s = 0; s < S; ++s) inv2s2[s] = 1.0f / (2.0f * sg[s] * sg[s]);

    const float cx = coords[3 * i + 0];
    const float cy = coords[3 * i + 1];
    const float cz = coords[3 * i + 2];

    float w[4][S];
    float part[S] = {0.f, 0.f, 0.f, 0.f};
#pragma unroll
    for (int c = 0; c < 4; ++c) {
        const int j = tid + c * 256;
        const float dx = cx - coords[3 * j + 0];
        const float dy = cy - coords[3 * j + 1];
        const float dz = cz - coords[3 * j + 2];
        const float d2 = dx * dx + dy * dy + dz * dz;
#pragma unroll
        for (int s = 0; s < S; ++s) {
            const float v = (j == i) ? 0.0f : expf(-d2 * inv2s2[s]);
            w[c][s] = v;
            part[s] += v;
        }
    }

    __shared__ float red[S][256];
#pragma unroll
    for (int s = 0; s < S; ++s) red[s][tid] = part[s];
    __syncthreads();
    for (int st = 128; st > 0; st >>= 1) {
        if (tid < st) {
#pragma unroll
            for (int s = 0; s < S; ++s) red[s][tid] += red[s][tid + st];
        }
        __syncthreads();
    }

    float invden[S];
#pragma unroll
    for (int s = 0; s < S; ++s) invden[s] = 1.0f / fmaxf(red[s][0], 1e-12f);

#pragma unroll
    for (int c = 0; c < 4; ++c) {
        const int j = tid + c * 256;
#pragma unroll
        for (int s = 0; s < S; ++s) {
            const float p = w[c][s] * invden[s];
            const size_t off = ((size_t)s * N + i) * N + j;
            const ushort h = f2bf(p);
            Oh[off] = h;
            Ol[off] = f2bf(p - bf2f(h));
        }
    }
}

// ---------------------------------------------------------------------------
// Kernel 2: transpose hi/lo pair (re-splitting the summed value).
// Yh+Yl = (Xh+Xl)^T per sigma. 64x64 tiles, LDS padded 64x65.
// ---------------------------------------------------------------------------
__global__ __launch_bounds__(256) void transpose_hl(const ushort* __restrict__ Xh,
                                                    const ushort* __restrict__ Xl,
                                                    ushort* __restrict__ Yh,
                                                    ushort* __restrict__ Yl)
{
    __shared__ float tile[64][65];
    const size_t zb = (size_t)blockIdx.z * N * N;
    const int tr = blockIdx.y * 64, tc = blockIdx.x * 64;
    const int tid = threadIdx.x;
    const int c  = tid & 63;
    const int r0 = tid >> 6;
#pragma unroll
    for (int i = 0; i < 16; ++i) {
        const int r = r0 + i * 4;
        const size_t idx = zb + (size_t)(tr + r) * N + tc + c;
        tile[r][c] = bf2f(Xh[idx]) + bf2f(Xl[idx]);
    }
    __syncthreads();
#pragma unroll
    for (int i = 0; i < 16; ++i) {
        const int r = r0 + i * 4;
        const size_t idx = zb + (size_t)(tc + r) * N + tr + c;
        const float x = tile[c][r];
        const ushort h = f2bf(x);
        Yh[idx] = h;
        Yl[idx] = f2bf(x - bf2f(h));
    }
}

// ---------------------------------------------------------------------------
// Kernel 3: split-bf16 MFMA GEMM.  C = (Ah+Al) @ (B) with B given transposed
// as hi/lo pair BT = B^T.  C written as fresh hi/lo bf16 pair.
// 1 wave per block, 64x64 output per wave, BK=32, counted-vmcnt double buffer,
// no barriers. LDS chunk swizzle: 16B chunk (row,kg) at slot row*4+(kg^((row>>1)&3)).
// ---------------------------------------------------------------------------
__global__ __launch_bounds__(64) void gemm_split(const ushort* __restrict__ Ah,
                                                 const ushort* __restrict__ Al,
                                                 const ushort* __restrict__ BTh,
                                                 const ushort* __restrict__ BTl,
                                                 ushort* __restrict__ Ch,
                                                 ushort* __restrict__ Cl)
{
    __shared__ ushort smem[2][4][2048];   // [buf][part: Ah,Al,Bh,Bl][64 rows x 32 k]
    const int lane = threadIdx.x;
    const size_t zb = (size_t)blockIdx.z * N * N;
    const int tr = blockIdx.y * 64;
    const int tc = blockIdx.x * 64;

    const ushort* gA0 = Ah  + zb + (size_t)tr * N;
    const ushort* gA1 = Al  + zb + (size_t)tr * N;
    const ushort* gB0 = BTh + zb + (size_t)tc * N;
    const ushort* gB1 = BTl + zb + (size_t)tc * N;

    f32x4 acc[4][4] = {};

    auto STAGE = [&](int bufi, int k0) __attribute__((always_inline)) {
#pragma unroll
        for (int b = 0; b < 4; ++b) {
            const int slot = b * 64 + lane;
            const int row  = slot >> 2;
            const int kg   = (slot & 3) ^ ((row >> 1) & 3);
            const size_t go = (size_t)row * N + k0 + kg * 8;
            gload16(gA0 + go, &smem[bufi][0][b * 512]);
            gload16(gA1 + go, &smem[bufi][1][b * 512]);
            gload16(gB0 + go, &smem[bufi][2][b * 512]);
            gload16(gB1 + go, &smem[bufi][3][b * 512]);
        }
    };

    const int lrow = lane & 15;
    const int lkg  = lane >> 4;

    auto COMPUTE = [&](int bufi) __attribute__((always_inline)) {
        short8 ah[4], al[4], bh[4], bl[4];
#pragma unroll
        for (int m = 0; m < 4; ++m) {
            const int row = m * 16 + lrow;
            const int off = row * 32 + ((lkg ^ ((row >> 1) & 3)) << 3);
            ah[m] = *(const short8*)&smem[bufi][0][off];
            al[m] = *(const short8*)&smem[bufi][1][off];
            bh[m] = *(const short8*)&smem[bufi][2][off];
            bl[m] = *(const short8*)&smem[bufi][3][off];
        }
#pragma unroll
        for (int m = 0; m < 4; ++m)
#pragma unroll
            for (int n = 0; n < 4; ++n) {
                acc[m][n] = __builtin_amdgcn_mfma_f32_16x16x32_bf16(ah[m], bh[n], acc[m][n], 0, 0, 0);
                acc[m][n] = __builtin_amdgcn_mfma_f32_16x16x32_bf16(ah[m], bl[n], acc[m][n], 0, 0, 0);
                acc[m][n] = __builtin_amdgcn_mfma_f32_16x16x32_bf16(al[m], bh[n], acc[m][n], 0, 0, 0);
            }
    };

    STAGE(0, 0);
#pragma unroll 1
    for (int t = 0; t < 16; ++t) {
        // half A: prefetch tile 2t+1 into buf1, compute tile 2t from buf0
        __builtin_amdgcn_sched_barrier(0);
        STAGE(1, (2 * t + 1) * 32);
        asm volatile("s_waitcnt vmcnt(16)" ::: "memory");
        __builtin_amdgcn_sched_barrier(0);
        COMPUTE(0);
        // half B: prefetch tile 2t+2 into buf0 (unless done), compute tile 2t+1
        __builtin_amdgcn_sched_barrier(0);
        if (t < 15) {
            STAGE(0, (2 * t + 2) * 32);
            asm volatile("s_waitcnt vmcnt(16)" ::: "memory");
        } else {
            asm volatile("s_waitcnt vmcnt(0)" ::: "memory");
        }
        __builtin_amdgcn_sched_barrier(0);
        COMPUTE(1);
    }

    // epilogue: fp32 acc -> fresh hi/lo bf16 pair
#pragma unroll
    for (int m = 0; m < 4; ++m)
#pragma unroll
        for (int n = 0; n < 4; ++n) {
            const f32x4 v = acc[m][n];
#pragma unroll
            for (int r = 0; r < 4; ++r) {
                const int row = tr + m * 16 + lkg * 4 + r;
                const int col = tc + n * 16 + lrow;
                const size_t idx = zb + (size_t)row * N + col;
                const float x = v[r];
                const ushort h = f2bf(x);
                Ch[idx] = h;
                Cl[idx] = f2bf(x - bf2f(h));
            }
        }
}

// ---------------------------------------------------------------------------
// Kernel 4: gather diag + edges from hi/lo pair into feature slot t.
// ---------------------------------------------------------------------------
__global__ __launch_bounds__(256) void gather_hl(const ushort* __restrict__ Ph,
                                                 const ushort* __restrict__ Pl,
                                                 const int* __restrict__ eidx,
                                                 float* __restrict__ out,
                                                 int t)
{
    const int tid = blockIdx.x * blockDim.x + threadIdx.x;
    const int ND = S * N;
    if (tid < ND) {
        const int s = tid >> 10;           // /N
        const int n = tid & (N - 1);
        const size_t off = ((size_t)s * N + n) * N + n;
        out[(size_t)n * FEAT + s * STEPS + t] = bf2f(Ph[off]) + bf2f(Pl[off]);
    } else {
        const int idx = tid - ND;
        if (idx >= S * NE) return;
        const int s = idx >> 15;           // /NE
        const int e = idx & (NE - 1);
        const int i = eidx[e];
        const int j = eidx[NE + e];
        const size_t off = ((size_t)s * N + i) * N + j;
        out[(size_t)N * FEAT + (size_t)e * FEAT + s * STEPS + t] =
            bf2f(Ph[off]) + bf2f(Pl[off]);
    }
}

// ---------------------------------------------------------------------------
extern "C" void kernel_launch(void* const* d_in, const int* in_sizes, int n_in,
                              void* d_out, int out_size, void* d_ws, size_t ws_size,
                              hipStream_t stream)
{
    const float* coords     = (const float*)d_in[0];
    const float* log_sigmas = (const float*)d_in[1];
    const int*   eidx       = (const int*)d_in[2];
    float*       out        = (float*)d_out;

    ushort* ping_h = (ushort*)d_ws;        // 6 x 8 MB = 48 MB total
    ushort* ping_l = ping_h + SZ;
    ushort* pong_h = ping_l + SZ;
    ushort* pong_l = pong_h + SZ;
    ushort* bt_h   = pong_l + SZ;
    ushort* bt_l   = bt_h   + SZ;

    build_P<<<N, 256, 0, stream>>>(coords, log_sigmas, ping_h, ping_l);

    const int gather_blocks = (S * N + S * NE + 255) / 256;   // 528
    gather_hl<<<gather_blocks, 256, 0, stream>>>(ping_h, ping_l, eidx, out, 0);

    transpose_hl<<<dim3(16, 16, S), 256, 0, stream>>>(ping_h, ping_l, bt_h, bt_l);

    ushort* cur_h = ping_h; ushort* cur_l = ping_l;
    ushort* nxt_h = pong_h; ushort* nxt_l = pong_l;
    for (int k = 2; k <= STEPS; ++k) {
        dim3 grid(N / 64, N / 64, S);
        gemm_split<<<grid, 64, 0, stream>>>(cur_h, cur_l, bt_h, bt_l, nxt_h, nxt_l);
        gather_hl<<<gather_blocks, 256, 0, stream>>>(nxt_h, nxt_l, eidx, out, k - 1);
        ushort* th = cur_h; ushort* tl = cur_l;
        cur_h = nxt_h; cur_l = nxt_l;
        nxt_h = th;    nxt_l = tl;
    }
}

// Round 3
// 771.502 us; speedup vs baseline: 4.9023x; 1.9276x over previous
//
#include <hip/hip_runtime.h>

#define N 1024
#define NE 32768
#define S 4
#define STEPS 31
#define FEAT (S * STEPS)  // 124
#define PLANE ((size_t)S * N * N)   // 4 Mi elements (8 MB as ushort)

typedef short short8 __attribute__((ext_vector_type(8)));
typedef float f32x4 __attribute__((ext_vector_type(4)));

// ---- bf16 helpers (RNE) ---------------------------------------------------
__device__ __forceinline__ ushort f2bf(float x) {
    union { float f; unsigned u; } v; v.f = x;
    unsigned r = v.u + 0x7fffu + ((v.u >> 16) & 1u);
    return (ushort)(r >> 16);
}
__device__ __forceinline__ float bf2f(ushort h) {
    union { unsigned u; float f; } v; v.u = ((unsigned)h) << 16;
    return v.f;
}

__device__ __forceinline__ void gload16(const ushort* g, ushort* l) {
    __builtin_amdgcn_global_load_lds(
        (const __attribute__((address_space(1))) unsigned int*)g,
        (__attribute__((address_space(3))) unsigned int*)l, 16, 0, 0);
}

// ---------------------------------------------------------------------------
// Kernel: build P (split bf16 hi/lo), row-major [s][i][j].
// ---------------------------------------------------------------------------
__global__ __launch_bounds__(256) void build_P(const float* __restrict__ coords,
                                               const float* __restrict__ log_sigmas,
                                               ushort* __restrict__ Oh,
                                               ushort* __restrict__ Ol)
{
    const int i   = blockIdx.x;
    const int tid = threadIdx.x;

    float sg[S];
#pragma unroll
    for (int s = 0; s < S; ++s) sg[s] = expf(log_sigmas[s]);
#define CSWP(a, b) { float lo = fminf(sg[a], sg[b]); float hi = fmaxf(sg[a], sg[b]); sg[a] = lo; sg[b] = hi; }
    CSWP(0, 1) CSWP(2, 3) CSWP(0, 2) CSWP(1, 3) CSWP(1, 2)
#undef CSWP
    float inv2s2[S];
#pragma unroll
    for (int s = 0; s < S; ++s) inv2s2[s] = 1.0f / (2.0f * sg[s] * sg[s]);

    const float cx = coords[3 * i + 0];
    const float cy = coords[3 * i + 1];
    const float cz = coords[3 * i + 2];

    float w[4][S];
    float part[S] = {0.f, 0.f, 0.f, 0.f};
#pragma unroll
    for (int c = 0; c < 4; ++c) {
        const int j = tid + c * 256;
        const float dx = cx - coords[3 * j + 0];
        const float dy = cy - coords[3 * j + 1];
        const float dz = cz - coords[3 * j + 2];
        const float d2 = dx * dx + dy * dy + dz * dz;
#pragma unroll
        for (int s = 0; s < S; ++s) {
            const float v = (j == i) ? 0.0f : expf(-d2 * inv2s2[s]);
            w[c][s] = v;
            part[s] += v;
        }
    }

    __shared__ float red[S][256];
#pragma unroll
    for (int s = 0; s < S; ++s) red[s][tid] = part[s];
    __syncthreads();
    for (int st = 128; st > 0; st >>= 1) {
        if (tid < st) {
#pragma unroll
            for (int s = 0; s < S; ++s) red[s][tid] += red[s][tid + st];
        }
        __syncthreads();
    }

    float invden[S];
#pragma unroll
    for (int s = 0; s < S; ++s) invden[s] = 1.0f / fmaxf(red[s][0], 1e-12f);

#pragma unroll
    for (int c = 0; c < 4; ++c) {
        const int j = tid + c * 256;
#pragma unroll
        for (int s = 0; s < S; ++s) {
            const float p = w[c][s] * invden[s];
            const size_t off = ((size_t)s * N + i) * N + j;
            const ushort h = f2bf(p);
            Oh[off] = h;
            Ol[off] = f2bf(p - bf2f(h));
        }
    }
}

// ---------------------------------------------------------------------------
// Kernel: transpose hi/lo pair, re-splitting the summed value.
// Yl may be null (hi-only output for extraction operands).
// ---------------------------------------------------------------------------
__global__ __launch_bounds__(256) void transpose_hl(const ushort* __restrict__ Xh,
                                                    const ushort* __restrict__ Xl,
                                                    ushort* __restrict__ Yh,
                                                    ushort* __restrict__ Yl)
{
    __shared__ float tile[64][65];
    const size_t zb = (size_t)blockIdx.z * N * N;
    const int tr = blockIdx.y * 64, tc = blockIdx.x * 64;
    const int tid = threadIdx.x;
    const int c  = tid & 63;
    const int r0 = tid >> 6;
#pragma unroll
    for (int i = 0; i < 16; ++i) {
        const int r = r0 + i * 4;
        const size_t idx = zb + (size_t)(tr + r) * N + tc + c;
        tile[r][c] = bf2f(Xh[idx]) + bf2f(Xl[idx]);
    }
    __syncthreads();
#pragma unroll
    for (int i = 0; i < 16; ++i) {
        const int r = r0 + i * 4;
        const size_t idx = zb + (size_t)(tc + r) * N + tr + c;
        const float x = tile[c][r];
        const ushort h = f2bf(x);
        Yh[idx] = h;
        if (Yl) Yl[idx] = f2bf(x - bf2f(h));
    }
}

// ---------------------------------------------------------------------------
// Kernel: split-bf16 MFMA GEMM (proven round-2).  C = (Ah+Al)@(B), B given
// transposed hi/lo.  Cl may be null (hi-only output).
// ---------------------------------------------------------------------------
__global__ __launch_bounds__(64) void gemm_split(const ushort* __restrict__ Ah,
                                                 const ushort* __restrict__ Al,
                                                 const ushort* __restrict__ BTh,
                                                 const ushort* __restrict__ BTl,
                                                 ushort* __restrict__ Ch,
                                                 ushort* __restrict__ Cl)
{
    __shared__ ushort smem[2][4][2048];
    const int lane = threadIdx.x;
    const size_t zb = (size_t)blockIdx.z * N * N;
    const int tr = blockIdx.y * 64;
    const int tc = blockIdx.x * 64;

    const ushort* gA0 = Ah  + zb + (size_t)tr * N;
    const ushort* gA1 = Al  + zb + (size_t)tr * N;
    const ushort* gB0 = BTh + zb + (size_t)tc * N;
    const ushort* gB1 = BTl + zb + (size_t)tc * N;

    f32x4 acc[4][4] = {};

    auto STAGE = [&](int bufi, int k0) __attribute__((always_inline)) {
#pragma unroll
        for (int b = 0; b < 4; ++b) {
            const int slot = b * 64 + lane;
            const int row  = slot >> 2;
            const int kg   = (slot & 3) ^ ((row >> 1) & 3);
            const size_t go = (size_t)row * N + k0 + kg * 8;
            gload16(gA0 + go, &smem[bufi][0][b * 512]);
            gload16(gA1 + go, &smem[bufi][1][b * 512]);
            gload16(gB0 + go, &smem[bufi][2][b * 512]);
            gload16(gB1 + go, &smem[bufi][3][b * 512]);
        }
    };

    const int lrow = lane & 15;
    const int lkg  = lane >> 4;

    auto COMPUTE = [&](int bufi) __attribute__((always_inline)) {
        short8 ah[4], al[4], bh[4], bl[4];
#pragma unroll
        for (int m = 0; m < 4; ++m) {
            const int row = m * 16 + lrow;
            const int off = row * 32 + ((lkg ^ ((row >> 1) & 3)) << 3);
            ah[m] = *(const short8*)&smem[bufi][0][off];
            al[m] = *(const short8*)&smem[bufi][1][off];
            bh[m] = *(const short8*)&smem[bufi][2][off];
            bl[m] = *(const short8*)&smem[bufi][3][off];
        }
#pragma unroll
        for (int m = 0; m < 4; ++m)
#pragma unroll
            for (int n = 0; n < 4; ++n) {
                acc[m][n] = __builtin_amdgcn_mfma_f32_16x16x32_bf16(ah[m], bh[n], acc[m][n], 0, 0, 0);
                acc[m][n] = __builtin_amdgcn_mfma_f32_16x16x32_bf16(ah[m], bl[n], acc[m][n], 0, 0, 0);
                acc[m][n] = __builtin_amdgcn_mfma_f32_16x16x32_bf16(al[m], bh[n], acc[m][n], 0, 0, 0);
            }
    };

    STAGE(0, 0);
#pragma unroll 1
    for (int t = 0; t < 16; ++t) {
        __builtin_amdgcn_sched_barrier(0);
        STAGE(1, (2 * t + 1) * 32);
        asm volatile("s_waitcnt vmcnt(16)" ::: "memory");
        __builtin_amdgcn_sched_barrier(0);
        COMPUTE(0);
        __builtin_amdgcn_sched_barrier(0);
        if (t < 15) {
            STAGE(0, (2 * t + 2) * 32);
            asm volatile("s_waitcnt vmcnt(16)" ::: "memory");
        } else {
            asm volatile("s_waitcnt vmcnt(0)" ::: "memory");
        }
        __builtin_amdgcn_sched_barrier(0);
        COMPUTE(1);
    }

#pragma unroll
    for (int m = 0; m < 4; ++m)
#pragma unroll
        for (int n = 0; n < 4; ++n) {
            const f32x4 v = acc[m][n];
#pragma unroll
            for (int r = 0; r < 4; ++r) {
                const int row = tr + m * 16 + lkg * 4 + r;
                const int col = tc + n * 16 + lrow;
                const size_t idx = zb + (size_t)row * N + col;
                const float x = v[r];
                const ushort h = f2bf(x);
                Ch[idx] = h;
                if (Cl) Cl[idx] = f2bf(x - bf2f(h));
            }
        }
}

// ---------------------------------------------------------------------------
// Kernel: gather diag + edges of a stored power into feature slot t.
// Pl may be null.
// ---------------------------------------------------------------------------
__global__ __launch_bounds__(256) void gather_hl(const ushort* __restrict__ Ph,
                                                 const ushort* __restrict__ Pl,
                                                 const int* __restrict__ eidx,
                                                 float* __restrict__ out,
                                                 int t)
{
    const int tid = blockIdx.x * blockDim.x + threadIdx.x;
    const int ND = S * N;
    if (tid < ND) {
        const int s = tid >> 10;
        const int n = tid & (N - 1);
        const size_t off = ((size_t)s * N + n) * N + n;
        float v = bf2f(Ph[off]);
        if (Pl) v += bf2f(Pl[off]);
        out[(size_t)n * FEAT + s * STEPS + t] = v;
    } else {
        const int idx = tid - ND;
        if (idx >= S * NE) return;
        const int s = idx >> 15;
        const int e = idx & (NE - 1);
        const int i = eidx[e];
        const int j = eidx[NE + e];
        const size_t off = ((size_t)s * N + i) * N + j;
        float v = bf2f(Ph[off]);
        if (Pl) v += bf2f(Pl[off]);
        out[(size_t)N * FEAT + (size_t)e * FEAT + s * STEPS + t] = v;
    }
}

// ---------------------------------------------------------------------------
// Bucketing (counting sort of edges by destination column j = eidx[NE+e]).
// ---------------------------------------------------------------------------
__global__ __launch_bounds__(256) void zero_aux(int* __restrict__ p, int n)
{
    for (int i = blockIdx.x * 256 + threadIdx.x; i < n; i += gridDim.x * 256) p[i] = 0;
}

__global__ __launch_bounds__(256) void edge_hist(const int* __restrict__ eidx,
                                                 int* __restrict__ hist)
{
    const int e = blockIdx.x * 256 + threadIdx.x;
    if (e < NE) atomicAdd(&hist[eidx[NE + e]], 1);
}

__global__ __launch_bounds__(1024) void scan1024(const int* __restrict__ hist,
                                                 int* __restrict__ offs)
{
    __shared__ int tmp[1024];
    const int t = threadIdx.x;
    tmp[t] = hist[t];
    __syncthreads();
    for (int d = 1; d < 1024; d <<= 1) {
        int v = (t >= d) ? tmp[t - d] : 0;
        __syncthreads();
        tmp[t] += v;
        __syncthreads();
    }
    offs[t + 1] = tmp[t];
    if (t == 0) offs[0] = 0;
}

__global__ __launch_bounds__(256) void edge_scatter(const int* __restrict__ eidx,
                                                    const int* __restrict__ offs,
                                                    int* __restrict__ cursor,
                                                    int* __restrict__ perm)
{
    const int e = blockIdx.x * 256 + threadIdx.x;
    if (e < NE) {
        const int j = eidx[NE + e];
        const int pos = atomicAdd(&cursor[j], 1);
        perm[offs[j] + pos] = e;
    }
}

// ---------------------------------------------------------------------------
// Kernel: extraction.  Block = (column j, sigma s).  Loads BT_b[j,:] rows for
// b=1..7 into LDS; each wave takes one task (edge with ej==j, or the diag
// (j,j)) and computes 21 dots: k = a + b for a in {8,16,24}, b in 1..7.
// All operands hi-only bf16; dots in fp32; butterfly-reduced over 64 lanes.
// ---------------------------------------------------------------------------
__global__ __launch_bounds__(256) void extract_k(const ushort* __restrict__ BTe,  // 7 planes
                                                 const ushort* __restrict__ A8,
                                                 const ushort* __restrict__ A16,
                                                 const ushort* __restrict__ A24,
                                                 const int* __restrict__ eidx,
                                                 const int* __restrict__ perm,
                                                 const int* __restrict__ offs,
                                                 float* __restrict__ out)
{
    const int j = blockIdx.x;
    const int s = blockIdx.y;
    const int tid  = threadIdx.x;
    const int wave = tid >> 6;
    const int lane = tid & 63;

    __shared__ ushort bt[7][1024];
    // stage 7 BT rows (896 chunks of 8 elems)
    for (int c = tid; c < 896; c += 256) {
        const int b  = c >> 7;
        const int ch = c & 127;
        *(short8*)&bt[b][ch * 8] =
            *(const short8*)&BTe[(size_t)b * PLANE + ((size_t)s * N + j) * N + ch * 8];
    }
    __syncthreads();

    const int base = offs[j];
    const int cnt  = offs[j + 1] - base;

    for (int task = wave; task <= cnt; task += 4) {
        int e = -1, i;
        if (task < cnt) { e = perm[base + task]; i = eidx[e]; }
        else            { i = j; }

        // load A rows (16 elems per lane per row), convert to f32
        float af[3][16];
        const ushort* Ap0 = A8  + ((size_t)s * N + i) * N + lane * 16;
        const ushort* Ap1 = A16 + ((size_t)s * N + i) * N + lane * 16;
        const ushort* Ap2 = A24 + ((size_t)s * N + i) * N + lane * 16;
        {
            short8 v0, v1;
            v0 = *(const short8*)Ap0; v1 = *(const short8*)(Ap0 + 8);
#pragma unroll
            for (int x = 0; x < 8; ++x) { af[0][x] = bf2f((ushort)v0[x]); af[0][8 + x] = bf2f((ushort)v1[x]); }
            v0 = *(const short8*)Ap1; v1 = *(const short8*)(Ap1 + 8);
#pragma unroll
            for (int x = 0; x < 8; ++x) { af[1][x] = bf2f((ushort)v0[x]); af[1][8 + x] = bf2f((ushort)v1[x]); }
            v0 = *(const short8*)Ap2; v1 = *(const short8*)(Ap2 + 8);
#pragma unroll
            for (int x = 0; x < 8; ++x) { af[2][x] = bf2f((ushort)v0[x]); af[2][8 + x] = bf2f((ushort)v1[x]); }
        }

        float part[21];
#pragma unroll
        for (int p = 0; p < 21; ++p) part[p] = 0.0f;

#pragma unroll
        for (int b = 0; b < 7; ++b) {
            const short8 w0 = *(const short8*)&bt[b][lane * 16];
            const short8 w1 = *(const short8*)&bt[b][lane * 16 + 8];
            float bf[16];
#pragma unroll
            for (int x = 0; x < 8; ++x) { bf[x] = bf2f((ushort)w0[x]); bf[8 + x] = bf2f((ushort)w1[x]); }
#pragma unroll
            for (int a = 0; a < 3; ++a)
#pragma unroll
                for (int x = 0; x < 16; ++x)
                    part[a * 7 + b] = fmaf(af[a][x], bf[x], part[a * 7 + b]);
        }

        // butterfly reduce across 64 lanes
#pragma unroll
        for (int d = 1; d < 64; d <<= 1)
#pragma unroll
            for (int p = 0; p < 21; ++p)
                part[p] += __shfl_xor(part[p], d, 64);

        if (lane == 0) {
            const size_t obase = (task < cnt)
                ? ((size_t)N * FEAT + (size_t)e * FEAT + (size_t)s * STEPS)
                : ((size_t)i * FEAT + (size_t)s * STEPS);
#pragma unroll
            for (int p = 0; p < 21; ++p) {
                const int a = (p / 7 == 0) ? 8 : (p / 7 == 1) ? 16 : 24;
                const int b = p % 7 + 1;
                out[obase + a + b - 1] = part[p];   // t = k-1 = a+b-1
            }
        }
    }
}

// ---------------------------------------------------------------------------
extern "C" void kernel_launch(void* const* d_in, const int* in_sizes, int n_in,
                              void* d_out, int out_size, void* d_ws, size_t ws_size,
                              hipStream_t stream)
{
    const float* coords     = (const float*)d_in[0];
    const float* log_sigmas = (const float*)d_in[1];
    const int*   eidx       = (const int*)d_in[2];
    float*       out        = (float*)d_out;

    ushort* W = (ushort*)d_ws;
    const int gather_blocks = (S * N + S * NE + 255) / 256;   // 528
    const dim3 ggrid(N / 64, N / 64, S);
    const dim3 tgrid(16, 16, S);

    // ---- plane map (each PLANE = 4Mi ushort = 8 MB) ----
    // scheme A (15 planes + aux):
    //  0:A0h 1:A0l 2:A1h 3:A1l 4:A2h 5:BT1l 6:BT8h 7:BT8l 8..14:BTe[b=1..7]h
    const size_t AUX_INTS = 1024 + 1025 + 1024 + NE;
    const size_t NEED_A   = 15 * PLANE * sizeof(ushort) + AUX_INTS * sizeof(int);

    if (ws_size >= NEED_A) {
        ushort* A0h = W + 0 * PLANE;  ushort* A0l = W + 1 * PLANE;
        ushort* A1h = W + 2 * PLANE;  ushort* A1l = W + 3 * PLANE;
        ushort* A2h = W + 4 * PLANE;
        ushort* BT1l = W + 5 * PLANE;
        ushort* BT8h = W + 6 * PLANE; ushort* BT8l = W + 7 * PLANE;
        ushort* BTe  = W + 8 * PLANE;           // 7 planes, b=1..7
        int* hist   = (int*)(W + 15 * PLANE);
        int* offs   = hist + 1024;
        int* cursor = offs + 1025;
        int* perm   = cursor + 1024;

        // edge bucketing by ej
        zero_aux<<<8, 256, 0, stream>>>(hist, 2048);          // hist + (offs head ok) -> hist,?; cursor below
        zero_aux<<<8, 256, 0, stream>>>(cursor, 1024);
        edge_hist<<<NE / 256, 256, 0, stream>>>(eidx, hist);
        scan1024<<<1, 1024, 0, stream>>>(hist, offs);
        edge_scatter<<<NE / 256, 256, 0, stream>>>(eidx, offs, cursor, perm);

        // P^1
        build_P<<<N, 256, 0, stream>>>(coords, log_sigmas, A0h, A0l);
        gather_hl<<<gather_blocks, 256, 0, stream>>>(A0h, A0l, eidx, out, 0);
        transpose_hl<<<tgrid, 256, 0, stream>>>(A0h, A0l, BTe + 0 * PLANE, BT1l);

        // chain P^2..P^8 (A alternates A0/A1; B = BT1 always)
        ushort* cur_h = A0h; ushort* cur_l = A0l;
        ushort* nxt_h = A1h; ushort* nxt_l = A1l;
        for (int m = 2; m <= 8; ++m) {
            gemm_split<<<ggrid, 64, 0, stream>>>(cur_h, cur_l, BTe, BT1l, nxt_h, nxt_l);
            gather_hl<<<gather_blocks, 256, 0, stream>>>(nxt_h, nxt_l, eidx, out, m - 1);
            if (m < 8)
                transpose_hl<<<tgrid, 256, 0, stream>>>(nxt_h, nxt_l,
                                                        BTe + (size_t)(m - 1) * PLANE, (ushort*)nullptr);
            else
                transpose_hl<<<tgrid, 256, 0, stream>>>(nxt_h, nxt_l, BT8h, BT8l);
            ushort* th = cur_h; ushort* tl = cur_l;
            cur_h = nxt_h; cur_l = nxt_l; nxt_h = th; nxt_l = tl;
        }
        // here: cur = P^8 (in A1), nxt = A0 free
        ushort* P8h = cur_h, *P8l = cur_l;
        ushort* P16h = nxt_h, *P16l = nxt_l;
        gemm_split<<<ggrid, 64, 0, stream>>>(P8h, P8l, BT8h, BT8l, P16h, P16l);
        gather_hl<<<gather_blocks, 256, 0, stream>>>(P16h, P16l, eidx, out, 15);
        gemm_split<<<ggrid, 64, 0, stream>>>(P16h, P16l, BT8h, BT8l, A2h, (ushort*)nullptr);
        gather_hl<<<gather_blocks, 256, 0, stream>>>(A2h, (ushort*)nullptr, eidx, out, 23);

        // extraction for k = 9..15, 17..23, 25..31
        extract_k<<<dim3(N, S), 256, 0, stream>>>(BTe, P8h, P16h, A2h, eidx, perm, offs, out);
    } else {
        // ---- fallback: proven round-2 linear chain (6 planes = 48 MB) ----
        ushort* ping_h = W + 0 * PLANE; ushort* ping_l = W + 1 * PLANE;
        ushort* pong_h = W + 2 * PLANE; ushort* pong_l = W + 3 * PLANE;
        ushort* bt_h   = W + 4 * PLANE; ushort* bt_l   = W + 5 * PLANE;

        build_P<<<N, 256, 0, stream>>>(coords, log_sigmas, ping_h, ping_l);
        gather_hl<<<gather_blocks, 256, 0, stream>>>(ping_h, ping_l, eidx, out, 0);
        transpose_hl<<<tgrid, 256, 0, stream>>>(ping_h, ping_l, bt_h, bt_l);

        ushort* cur_h = ping_h; ushort* cur_l = ping_l;
        ushort* nxt_h = pong_h; ushort* nxt_l = pong_l;
        for (int k = 2; k <= STEPS; ++k) {
            gemm_split<<<ggrid, 64, 0, stream>>>(cur_h, cur_l, bt_h, bt_l, nxt_h, nxt_l);
            gather_hl<<<gather_blocks, 256, 0, stream>>>(nxt_h, nxt_l, eidx, out, k - 1);
            ushort* th = cur_h; ushort* tl = cur_l;
            cur_h = nxt_h; cur_l = nxt_l; nxt_h = th; nxt_l = tl;
        }
    }
}